// Round 5
// baseline (405.495 us; speedup 1.0000x reference)
//
#include <hip/hip_runtime.h>
#include <hip/hip_bf16.h>

namespace {
constexpr int kL = 720, kF = 128;
constexpr int kWin = 15;
constexpr float kEps = 1e-6f;
constexpr float kMaxN = 1.0f - 1e-5f;
constexpr int kT0off = 360;   // (30-15)*24: only last 15 segments matter
constexpr int ZTR = 132;      // zt row stride (floats), +4 pad (fused fallback)
constexpr int AROW = 104;     // A lds row stride bf16 (fused fallback)
constexpr int AFR = 100;      // K1a fp32 A row stride (96 + 4 pad)
// ws offsets
constexpr size_t kOffT0   = 0;                    // 16 MiB bf16 t0
constexpr size_t kOffW1   = 16777216;             // 128 KiB bf16 W1 [n][k]
constexpr size_t kOffW2   = kOffW1 + 131072;      // 32 KiB bf16 W2 [p][k]
constexpr size_t kOffBt   = kOffW2 + 32768;       // 72 KiB: BtH/BtM/BtL [128][96] bf16
constexpr size_t kOffBsum = kOffBt + 73728;       // 512 B fp32 (=17014784)
constexpr size_t kOffZ2   = 17018880;             // 1 MiB fp32 z2 [16384][16]
constexpr size_t kOffHid  = 17825792;             // 64 MiB bf16 hid (lives k2a..k2b)
constexpr size_t kOffZ    = 18874368;             // 126 MiB fp32 z (lives k1a..k1b; overlaps hid OK)
constexpr size_t kWsSplit = kOffHid + 67108864;   // 84,934,656: split-K2 path
constexpr size_t kWsNew   = kOffZ + 125829120;    // 144,703,488: split-K1 path
}

typedef float f32x4 __attribute__((ext_vector_type(4)));
typedef short s16x8 __attribute__((ext_vector_type(8)));

__device__ __forceinline__ float rcp_f(float x) { return __builtin_amdgcn_rcpf(x); }
__device__ __forceinline__ float sqrt_f(float x) { return __builtin_amdgcn_sqrtf(x); }
__device__ __forceinline__ float tanh_f(float x) {          // x >= 0
  float t = __builtin_amdgcn_exp2f(x * -2.8853900817779268f);
  return (1.0f - t) * rcp_f(1.0f + t);
}
__device__ __forceinline__ float artanh_f(float n) {        // n >= 0
  float nc = fminf(n, 1.0f - 1e-7f);
  return 0.34657359027997264f * __builtin_amdgcn_logf((1.0f + nc) * rcp_f(1.0f - nc));
}

// DPP butterfly add helpers (VALU-latency cross-lane, no LDS pipe).
template<int CTRL>
__device__ __forceinline__ float dpp_add(float v) {
  int mv = __builtin_amdgcn_update_dpp(0, __float_as_int(v), CTRL, 0xF, 0xF, false);
  return v + __int_as_float(mv);
}
__device__ __forceinline__ float sum16(float v) {
  v = dpp_add<0xB1>(v);
  v = dpp_add<0x4E>(v);
  v = dpp_add<0x141>(v);
  v = dpp_add<0x128>(v);
  return v;
}
__device__ __forceinline__ float sum64(float v) {
  v = sum16(v);
  v += __shfl_xor(v, 16);
  v += __shfl_xor(v, 32);
  return v;
}
__device__ __forceinline__ float rlane(float v, int i) {
  return __int_as_float(__builtin_amdgcn_readlane(__float_as_int(v), i));
}
// RNE bf16: returns 16-bit pattern, and the rounded value as f32 via fval.
__device__ __forceinline__ unsigned short rne_bf16(float f, float& fval) {
  unsigned u = __float_as_uint(f);
  unsigned r = (u + 0x7FFFu + ((u >> 16) & 1u)) & 0xFFFF0000u;
  fval = __uint_as_float(r);
  return (unsigned short)(r >> 16);
}

// ---------------- prep: weight repack (bf16 W1/W2 + 3-level split Bt + bsum) ----------------
extern "C" __global__ __launch_bounds__(256)
void mwhf_prep(const float* __restrict__ W1, const float* __restrict__ W2,
               const float* __restrict__ W_t, const float* __restrict__ W_c,
               const float* __restrict__ W_f, const float* __restrict__ W_r,
               const float* __restrict__ b_t, const float* __restrict__ b_c,
               const float* __restrict__ b_f, const float* __restrict__ b_r,
               __hip_bfloat16* __restrict__ W1bf, __hip_bfloat16* __restrict__ W2bf,
               __hip_bfloat16* __restrict__ BtH, __hip_bfloat16* __restrict__ BtM,
               __hip_bfloat16* __restrict__ BtL, float* __restrict__ bsum)
{
  const int b = blockIdx.x, tid = threadIdx.x;
  if (b < 64) {                       // W1 [128k][512n] -> W1bf[n][k]
    const int n0 = b * 8;
    for (int e = tid; e < 1024; e += 256) {
      int n_l = e & 7, k = e >> 3;
      W1bf[(size_t)(n0 + n_l) * 128 + k] = __float2bfloat16(W1[(size_t)k * 512 + n0 + n_l]);
    }
  } else if (b < 68) {                // W2 [512k][24p] -> W2bf[p][k], rows 24..31 zero
    const int k0 = (b - 64) * 128;
    for (int e = tid; e < 4096; e += 256) {
      int p = e >> 7, k_l = e & 127;
      float v = (p < 24) ? W2[(size_t)(k0 + k_l) * 24 + p] : 0.0f;
      W2bf[(size_t)p * 512 + k0 + k_l] = __float2bfloat16(v);
    }
  } else if (b < 72) {                // Bt[d][k=st*24+s] = W_st[s][d], 3-level bf16 split
    const int st = b - 68;
    const float* src = (st == 0) ? W_t : (st == 1) ? W_c : (st == 2) ? W_f : W_r;
    for (int e = tid; e < 3072; e += 256) {
      int s = e >> 7, d = e & 127;
      float x = src[e];                       // src[s*128 + d]
      __hip_bfloat16 h = __float2bfloat16(x);
      float r1 = x - __bfloat162float(h);
      __hip_bfloat16 m = __float2bfloat16(r1);
      float r2 = r1 - __bfloat162float(m);
      const int o = d * 96 + st * 24 + s;
      BtH[o] = h;
      BtM[o] = m;
      BtL[o] = __float2bfloat16(r2);
    }
  } else {
    if (tid < 128) bsum[tid] = b_t[tid] + b_c[tid] + b_f[tid] + b_r[tid];
  }
}

// ---------------- K1a: stage1 GEMM (3-level bf16 MFMA, split-on-read) + expmap0 -> z ----
// fp32 A in LDS (25.6 KB, one barrier); B streamed from L2; z/z2 to workspace fp32.
extern "C" __global__ __launch_bounds__(256, 4)
void mwhf_k1a(const float* __restrict__ trend,
              const float* __restrict__ seas_c,
              const float* __restrict__ seas_f,
              const float* __restrict__ resid,
              const __hip_bfloat16* __restrict__ BtH,
              const __hip_bfloat16* __restrict__ BtM,
              const __hip_bfloat16* __restrict__ BtL,
              const float* __restrict__ bsum,
              float* __restrict__ z_ws, float* __restrict__ z2_ws)
{
  __shared__ __align__(16) float Af[64 * AFR];   // 25600 B, row m = feat*16 + seg

  const int tid = threadIdx.x;
  const int bix = blockIdx.x;
  const int bb = (bix & 7) * 16 + (bix >> 8);
  const int f0 = ((bix >> 3) & 31) * 4;
  const int row0 = bb * 128 + f0;

  // zero pad rows (m%16==15), cols 0..95
  for (int e = tid; e < 384; e += 256) {
    int rr = e / 96, cc = e - rr * 96;
    Af[(rr * 16 + 15) * AFR + cc] = 0.f;
  }
  {
    const float* ptrs[4] = {trend, seas_c, seas_f, resid};
    for (int e = tid; e < 1440; e += 256) {
      int seg = e / 96, k = e - seg * 96;
      int st = k / 24, s = k - st * 24;
      float4 v = *(const float4*)&ptrs[st][(size_t)(bb * kL + kT0off + seg * 24 + s) * kF + f0];
      Af[(0 * 16 + seg) * AFR + k] = v.x;
      Af[(1 * 16 + seg) * AFR + k] = v.y;
      Af[(2 * 16 + seg) * AFR + k] = v.z;
      Af[(3 * 16 + seg) * AFR + k] = v.w;
    }
  }
  __syncthreads();

  const int w = tid >> 6, lane = tid & 63;
  const int l16 = lane & 15, quad = lane >> 4;

  // build 3-level A frags from fp32 (hi = exact truncation split; mid/lo RNE)
  s16x8 ah[3], am[3], al[3];
  {
    const float* ar = &Af[(w * 16 + l16) * AFR + quad * 8];
#pragma unroll
    for (int ks = 0; ks < 3; ++ks) {
#pragma unroll
      for (int j = 0; j < 8; ++j) {
        float x = ar[ks * 32 + j];
        unsigned hu = __float_as_uint(x) & 0xFFFF0000u;
        float r1 = x - __uint_as_float(hu);
        float mf; unsigned short mb = rne_bf16(r1, mf);
        float r2 = r1 - mf;
        float lf; unsigned short lb = rne_bf16(r2, lf);
        (void)lf;
        ah[ks][j] = (short)(hu >> 16);
        am[ks][j] = (short)mb;
        al[ks][j] = (short)lb;
      }
    }
  }

  f32x4 acc0[8];
#pragma unroll
  for (int t = 0; t < 8; ++t) acc0[t] = (f32x4)0.f;
  const __hip_bfloat16* bhp = BtH + l16 * 96 + quad * 8;
  const __hip_bfloat16* bmp = BtM + l16 * 96 + quad * 8;
  const __hip_bfloat16* blp = BtL + l16 * 96 + quad * 8;
#pragma unroll
  for (int t = 0; t < 8; ++t) {
#pragma unroll
    for (int ks = 0; ks < 3; ++ks) {
      s16x8 bh = *(const s16x8*)(bhp + t * 1536 + ks * 32);
      s16x8 bm = *(const s16x8*)(bmp + t * 1536 + ks * 32);
      s16x8 bl = *(const s16x8*)(blp + t * 1536 + ks * 32);
      acc0[t] = __builtin_amdgcn_mfma_f32_16x16x32_bf16(ah[ks], bh, acc0[t], 0, 0, 0);
      acc0[t] = __builtin_amdgcn_mfma_f32_16x16x32_bf16(am[ks], bh, acc0[t], 0, 0, 0);
      acc0[t] = __builtin_amdgcn_mfma_f32_16x16x32_bf16(ah[ks], bm, acc0[t], 0, 0, 0);
      acc0[t] = __builtin_amdgcn_mfma_f32_16x16x32_bf16(al[ks], bh, acc0[t], 0, 0, 0);
      acc0[t] = __builtin_amdgcn_mfma_f32_16x16x32_bf16(ah[ks], bl, acc0[t], 0, 0, 0);
      acc0[t] = __builtin_amdgcn_mfma_f32_16x16x32_bf16(am[ks], bm, acc0[t], 0, 0, 0);
    }
  }
  // bias + per-row square-sums (row = quad*4+r = seg; col = t*16+l16 = d)
  float part[4] = {0.f, 0.f, 0.f, 0.f};
#pragma unroll
  for (int t = 0; t < 8; ++t) {
    float bv = bsum[t * 16 + l16];
#pragma unroll
    for (int r = 0; r < 4; ++r) {
      float v = acc0[t][r] + bv;
      acc0[t][r] = v;
      part[r] += v * v;
    }
  }
#pragma unroll
  for (int r = 0; r < 4; ++r) part[r] = sum16(part[r]);
  const int ro = row0 + w;
#pragma unroll
  for (int r = 0; r < 4; ++r) {
    const int seg = quad * 4 + r;
    float v2 = part[r];
    float nv = sqrt_f(fmaxf(v2, 1e-12f));
    float sc = tanh_f(nv) * rcp_f(nv);
    float y2 = sc * sc * v2;
    float yn = sqrt_f(fmaxf(y2, 1e-12f));
    float proj = (yn > kMaxN) ? (kMaxN * rcp_f(yn)) : 1.0f;
    float scl = sc * proj;
    if (seg < kWin) {
#pragma unroll
      for (int t = 0; t < 8; ++t)
        z_ws[(size_t)ro * 1920 + seg * 128 + t * 16 + l16] = acc0[t][r] * scl;
      if (l16 == 0) z2_ws[ro * 16 + seg] = y2 * proj * proj;
    }
  }
}

// ---------------- K1b: hyperbolic recurrence (barrier-free, high-TLP) -> t0 ----
// Verbatim R4 phase-2 structure; inputs from z/z2 workspace; wave w owns row ro.
extern "C" __global__ __launch_bounds__(256, 6)
void mwhf_k1b(const float* __restrict__ z_ws, const float* __restrict__ z2_ws,
              const float* __restrict__ alpha,
              __hip_bfloat16* __restrict__ t0_out)
{
  __shared__ float z2s[80];
  __shared__ float pds[80];
  const int tid = threadIdx.x;
  const int w = tid >> 6, l = tid & 63;
  const int ro = blockIdx.x * 4 + w;

  float zx[19], zy[19];
  const float* zr = z_ws + (size_t)ro * 1920;
#pragma unroll
  for (int j = 0; j < 15; ++j) {
    float2 v = *(const float2*)&zr[j * 128 + 2 * l];
    zx[j] = v.x; zy[j] = v.y;
  }
  if (l < 15) z2s[w * 20 + l] = z2_ws[ro * 16 + l];

  // initial 14 pair dot products -> pds LDS ring
  {
    float pd[14];
#pragma unroll
    for (int j = 0; j < 14; ++j) pd[j] = zx[j] * zx[j + 1] + zy[j] * zy[j + 1];
#pragma unroll
    for (int j = 0; j < 14; ++j) pd[j] = sum64(pd[j]);
    if (l == 0) {
#pragma unroll
      for (int j = 0; j < 14; ++j) pds[w * 20 + j] = pd[j];
    }
  }

  const float alp = alpha[0];
  const float cw14 = (l < 14)
      ? __builtin_amdgcn_exp2f((float)(13 - l) * -0.15200309344504997f) * 0.12966260f
      : 0.f;

#pragma unroll
  for (int it = 0; it < 4; ++it) {
    float cA = 0.f, cB = 0.f, cW = 0.f;
    if (l < 14) {
      float dp = pds[w * 20 + it + l];
      float x2 = z2s[w * 20 + it + l];
      float y2 = z2s[w * 20 + it + l + 1];
      cA = 1.f - 2.f * dp + y2;
      cB = 1.f - x2;
      float den = fmaxf(1.f - 2.f * dp + x2 * y2, kEps);
      float invd = rcp_f(den);
      float d2 = (cA * cA * x2 - 2.f * cA * cB * dp + cB * cB * y2) * (invd * invd);
      float n = sqrt_f(fmaxf(d2, 1e-12f));
      float coef = fmaxf(cB, kEps) * artanh_f(n) * rcp_f(n);
      cW = cw14 * coef * invd;
    }
    float avx = 0.f, avy = 0.f;
#pragma unroll
    for (int i = 0; i < 14; ++i) {
      float sA = rlane(cA, i), sB = rlane(cB, i), sW = rlane(cW, i);
      float tx = sB * zx[it + i + 1] - sA * zx[it + i];
      float ty = sB * zy[it + i + 1] - sA * zy[it + i];
      avx += sW * tx;
      avy += sW * ty;
    }
    float vx = alp * avx, vy = alp * avy;
    const int pl = it + 14;
    float x2l = z2s[w * 20 + pl];
    float v2 = vx * vx + vy * vy;
    float xdv = zx[pl] * vx + zy[pl] * vy;
    v2 = sum64(v2);
    xdv = sum64(xdv);
    float nv = sqrt_f(fmaxf(v2, 1e-12f));
    float lam = 2.f * rcp_f(fmaxf(1.f - x2l, kEps));
    float co = tanh_f(0.5f * lam * nv) * rcp_f(nv);
    float s2 = co * co * v2;
    float xy = co * xdv;
    float P = 1.f + 2.f * xy + s2;
    float Q = 1.f - x2l;
    float den2 = fmaxf(1.f + 2.f * xy + x2l * s2, kEps);
    float invd2 = rcp_f(den2);
    float znx = (P * zx[pl] + Q * co * vx) * invd2;
    float zny = (P * zy[pl] + Q * co * vy) * invd2;
    float zn2 = (P * P * x2l + 2.f * P * Q * xy + Q * Q * s2) * (invd2 * invd2);
    float pdn = (P * x2l + Q * xy) * invd2;
    float yn = sqrt_f(fmaxf(zn2, 1e-12f));
    float proj = (yn > kMaxN) ? (kMaxN * rcp_f(yn)) : 1.f;
    znx *= proj; zny *= proj;
    zn2 *= proj * proj;
    pdn *= proj;
    zx[15 + it] = znx; zy[15 + it] = zny;
    if (l == 0) {
      z2s[w * 20 + 15 + it] = zn2;
      pds[w * 20 + 14 + it] = pdn;
    }
    float n0 = sqrt_f(fmaxf(zn2, 1e-12f));
    float fac = artanh_f(n0) * rcp_f(n0);
    __hip_bfloat162 hv;
    hv.x = __float2bfloat16(fac * znx);
    hv.y = __float2bfloat16(fac * zny);
    *(__hip_bfloat162*)(t0_out + ((size_t)ro * 4 + it) * 128 + 2 * l) = hv;
  }
}

// ---------------- fused K1 (R4-verified) fallback if ws too small for z ----------------
extern "C" __global__ __launch_bounds__(256, 4)
void mwhf_k1(const float* __restrict__ trend,
             const float* __restrict__ seas_c,
             const float* __restrict__ seas_f,
             const float* __restrict__ resid,
             const __hip_bfloat16* __restrict__ BtH,
             const __hip_bfloat16* __restrict__ BtM,
             const __hip_bfloat16* __restrict__ BtL,
             const float* __restrict__ bsum,
             const float* __restrict__ alpha,
             __hip_bfloat16* __restrict__ t0_out)
{
  __shared__ __align__(16) char smem_raw[3 * 64 * AROW * 2];
  __shared__ float z2s[80];
  __shared__ float pds[80];

  float* ublk = (float*)smem_raw;
  __hip_bfloat16* Ah = (__hip_bfloat16*)smem_raw;
  __hip_bfloat16* Am = Ah + 64 * AROW;
  __hip_bfloat16* Al = Am + 64 * AROW;

  const int tid = threadIdx.x;
  const int bix = blockIdx.x;
  const int bb = (bix & 7) * 16 + (bix >> 8);
  const int f0 = ((bix >> 3) & 31) * 4;
  const int row0 = bb * 128 + f0;

  for (int e = tid; e < 192; e += 256) {
    int rr = e / 48, cc = e - rr * 48;
    int off = (rr * 16 + 15) * AROW;
    ((unsigned int*)(Ah + off))[cc] = 0u;
    ((unsigned int*)(Am + off))[cc] = 0u;
    ((unsigned int*)(Al + off))[cc] = 0u;
  }
  {
    const float* ptrs[4] = {trend, seas_c, seas_f, resid};
    for (int e = tid; e < 1440; e += 256) {
      int seg = e / 96;
      int k = e - seg * 96;
      int st = k / 24, s = k - st * 24;
      const float* p = ptrs[st];
      float4 v = *(const float4*)&p[(size_t)(bb * kL + kT0off + seg * 24 + s) * kF + f0];
      float xv[4] = {v.x, v.y, v.z, v.w};
#pragma unroll
      for (int f = 0; f < 4; ++f) {
        int m = f * 16 + seg;
        __hip_bfloat16 h = __float2bfloat16(xv[f]);
        float r1 = xv[f] - __bfloat162float(h);
        __hip_bfloat16 mm = __float2bfloat16(r1);
        float r2 = r1 - __bfloat162float(mm);
        Ah[m * AROW + k] = h;
        Am[m * AROW + k] = mm;
        Al[m * AROW + k] = __float2bfloat16(r2);
      }
    }
  }
  __syncthreads();

  const int w = tid >> 6;
  const int lane = tid & 63;
  const int l16 = lane & 15, quad = lane >> 4;

  f32x4 acc0[8];
  float scale4[4], zz4[4];
  {
    s16x8 ah[3], am[3], al[3];
    const int abase = (w * 16 + l16) * AROW + quad * 8;
#pragma unroll
    for (int ks = 0; ks < 3; ++ks) {
      ah[ks] = *(const s16x8*)(Ah + abase + ks * 32);
      am[ks] = *(const s16x8*)(Am + abase + ks * 32);
      al[ks] = *(const s16x8*)(Al + abase + ks * 32);
    }
#pragma unroll
    for (int t = 0; t < 8; ++t) acc0[t] = (f32x4)0.f;
    const __hip_bfloat16* bhp = BtH + l16 * 96 + quad * 8;
    const __hip_bfloat16* bmp = BtM + l16 * 96 + quad * 8;
    const __hip_bfloat16* blp = BtL + l16 * 96 + quad * 8;
#pragma unroll
    for (int t = 0; t < 8; ++t) {
#pragma unroll
      for (int ks = 0; ks < 3; ++ks) {
        s16x8 bh = *(const s16x8*)(bhp + t * 1536 + ks * 32);
        s16x8 bm = *(const s16x8*)(bmp + t * 1536 + ks * 32);
        s16x8 bl = *(const s16x8*)(blp + t * 1536 + ks * 32);
        acc0[t] = __builtin_amdgcn_mfma_f32_16x16x32_bf16(ah[ks], bh, acc0[t], 0, 0, 0);
        acc0[t] = __builtin_amdgcn_mfma_f32_16x16x32_bf16(am[ks], bh, acc0[t], 0, 0, 0);
        acc0[t] = __builtin_amdgcn_mfma_f32_16x16x32_bf16(ah[ks], bm, acc0[t], 0, 0, 0);
        acc0[t] = __builtin_amdgcn_mfma_f32_16x16x32_bf16(al[ks], bh, acc0[t], 0, 0, 0);
        acc0[t] = __builtin_amdgcn_mfma_f32_16x16x32_bf16(ah[ks], bl, acc0[t], 0, 0, 0);
        acc0[t] = __builtin_amdgcn_mfma_f32_16x16x32_bf16(am[ks], bm, acc0[t], 0, 0, 0);
      }
    }
    float part[4] = {0.f, 0.f, 0.f, 0.f};
#pragma unroll
    for (int t = 0; t < 8; ++t) {
      float bv = bsum[t * 16 + l16];
#pragma unroll
      for (int r = 0; r < 4; ++r) {
        float v = acc0[t][r] + bv;
        acc0[t][r] = v;
        part[r] += v * v;
      }
    }
#pragma unroll
    for (int r = 0; r < 4; ++r) part[r] = sum16(part[r]);
#pragma unroll
    for (int r = 0; r < 4; ++r) {
      float v2 = part[r];
      float nv = sqrt_f(fmaxf(v2, 1e-12f));
      float sc = tanh_f(nv) * rcp_f(nv);
      float y2 = sc * sc * v2;
      float yn = sqrt_f(fmaxf(y2, 1e-12f));
      float proj = (yn > kMaxN) ? (kMaxN * rcp_f(yn)) : 1.0f;
      scale4[r] = sc * proj;
      zz4[r] = y2 * proj * proj;
    }
  }
  __syncthreads();
  {
#pragma unroll
    for (int r = 0; r < 4; ++r) {
      int row = quad * 4 + r;
      if (row < kWin) {
#pragma unroll
        for (int t = 0; t < 8; ++t)
          ublk[(w * kWin + row) * ZTR + t * 16 + l16] = acc0[t][r] * scale4[r];
        if (l16 == 0) z2s[w * 20 + row] = zz4[r];
      }
    }
  }
  __syncthreads();

  {
    const int l = lane;
    float zx[19], zy[19];
#pragma unroll
    for (int j = 0; j < 15; ++j) {
      float2 v = *(const float2*)&ublk[(w * kWin + j) * ZTR + 2 * l];
      zx[j] = v.x; zy[j] = v.y;
    }
    {
      float pd[14];
#pragma unroll
      for (int j = 0; j < 14; ++j) pd[j] = zx[j] * zx[j + 1] + zy[j] * zy[j + 1];
#pragma unroll
      for (int j = 0; j < 14; ++j) pd[j] = sum64(pd[j]);
      if (l == 0) {
#pragma unroll
        for (int j = 0; j < 14; ++j) pds[w * 20 + j] = pd[j];
      }
    }
    const float alp = alpha[0];
    const float cw14 = (l < 14)
        ? __builtin_amdgcn_exp2f((float)(13 - l) * -0.15200309344504997f) * 0.12966260f
        : 0.f;
#pragma unroll
    for (int it = 0; it < 4; ++it) {
      float cA = 0.f, cB = 0.f, cW = 0.f;
      if (l < 14) {
        float dp = pds[w * 20 + it + l];
        float x2 = z2s[w * 20 + it + l];
        float y2 = z2s[w * 20 + it + l + 1];
        cA = 1.f - 2.f * dp + y2;
        cB = 1.f - x2;
        float den = fmaxf(1.f - 2.f * dp + x2 * y2, kEps);
        float invd = rcp_f(den);
        float d2 = (cA * cA * x2 - 2.f * cA * cB * dp + cB * cB * y2) * (invd * invd);
        float n = sqrt_f(fmaxf(d2, 1e-12f));
        float coef = fmaxf(cB, kEps) * artanh_f(n) * rcp_f(n);
        cW = cw14 * coef * invd;
      }
      float avx = 0.f, avy = 0.f;
#pragma unroll
      for (int i = 0; i < 14; ++i) {
        float sA = rlane(cA, i), sB = rlane(cB, i), sW = rlane(cW, i);
        float tx = sB * zx[it + i + 1] - sA * zx[it + i];
        float ty = sB * zy[it + i + 1] - sA * zy[it + i];
        avx += sW * tx;
        avy += sW * ty;
      }
      float vx = alp * avx, vy = alp * avy;
      const int pl = it + 14;
      float x2l = z2s[w * 20 + pl];
      float v2 = vx * vx + vy * vy;
      float xdv = zx[pl] * vx + zy[pl] * vy;
      v2 = sum64(v2);
      xdv = sum64(xdv);
      float nv = sqrt_f(fmaxf(v2, 1e-12f));
      float lam = 2.f * rcp_f(fmaxf(1.f - x2l, kEps));
      float co = tanh_f(0.5f * lam * nv) * rcp_f(nv);
      float s2 = co * co * v2;
      float xy = co * xdv;
      float P = 1.f + 2.f * xy + s2;
      float Q = 1.f - x2l;
      float den2 = fmaxf(1.f + 2.f * xy + x2l * s2, kEps);
      float invd2 = rcp_f(den2);
      float znx = (P * zx[pl] + Q * co * vx) * invd2;
      float zny = (P * zy[pl] + Q * co * vy) * invd2;
      float zn2 = (P * P * x2l + 2.f * P * Q * xy + Q * Q * s2) * (invd2 * invd2);
      float pdn = (P * x2l + Q * xy) * invd2;
      float yn = sqrt_f(fmaxf(zn2, 1e-12f));
      float proj = (yn > kMaxN) ? (kMaxN * rcp_f(yn)) : 1.f;
      znx *= proj; zny *= proj;
      zn2 *= proj * proj;
      pdn *= proj;
      zx[15 + it] = znx; zy[15 + it] = zny;
      if (l == 0) {
        z2s[w * 20 + 15 + it] = zn2;
        pds[w * 20 + 14 + it] = pdn;
      }
      float n0 = sqrt_f(fmaxf(zn2, 1e-12f));
      float fac = artanh_f(n0) * rcp_f(n0);
      __hip_bfloat162 hv;
      hv.x = __float2bfloat16(fac * znx);
      hv.y = __float2bfloat16(fac * zny);
      *(__hip_bfloat162*)(t0_out + ((size_t)(row0 + w) * 4 + it) * 128 + 2 * l) = hv;
    }
  }
}

// ---------------- K2a: hid = relu(t0 @ W1 + b1), LDS-free streaming MFMA ----------------
extern "C" __global__ __launch_bounds__(256, 4)
void mwhf_k2a(const __hip_bfloat16* __restrict__ t0g,
              const __hip_bfloat16* __restrict__ W1bf,
              const float* __restrict__ b1,
              __hip_bfloat16* __restrict__ hid)
{
  const int tid = threadIdx.x;
  const int w = tid >> 6, lane = tid & 63;
  const int l16 = lane & 15, quad = lane >> 4;
  const int mbase = blockIdx.x * 32;
  const int ng = w * 128;

  s16x8 afr[2][4];
#pragma unroll
  for (int s = 0; s < 2; ++s)
#pragma unroll
    for (int kc = 0; kc < 4; ++kc)
      afr[s][kc] = *(const s16x8*)(t0g + (size_t)(mbase + s * 16 + l16) * 128 + kc * 32 + quad * 8);

  f32x4 acc[2][8];
#pragma unroll
  for (int s = 0; s < 2; ++s)
#pragma unroll
    for (int t = 0; t < 8; ++t) acc[s][t] = (f32x4)0.f;

#pragma unroll
  for (int t = 0; t < 8; ++t) {
    const __hip_bfloat16* bp = W1bf + (size_t)(ng + t * 16 + l16) * 128 + quad * 8;
#pragma unroll
    for (int kc = 0; kc < 4; ++kc) {
      s16x8 bfr = *(const s16x8*)(bp + kc * 32);
      acc[0][t] = __builtin_amdgcn_mfma_f32_16x16x32_bf16(afr[0][kc], bfr, acc[0][t], 0, 0, 0);
      acc[1][t] = __builtin_amdgcn_mfma_f32_16x16x32_bf16(afr[1][kc], bfr, acc[1][t], 0, 0, 0);
    }
  }
#pragma unroll
  for (int t = 0; t < 8; ++t) {
    const int n = ng + t * 16 + l16;
    float bv = b1[n];
#pragma unroll
    for (int s = 0; s < 2; ++s)
#pragma unroll
      for (int r = 0; r < 4; ++r) {
        int m = mbase + s * 16 + quad * 4 + r;
        float h = fmaxf(acc[s][t][r] + bv, 0.f);
        hid[(size_t)m * 512 + n] = __float2bfloat16(h);
      }
  }
}

// ---------------- K2b: out = hid @ W2 + b2, scattered to (b, 96, f) ----------------
extern "C" __global__ __launch_bounds__(256, 4)
void mwhf_k2b(const __hip_bfloat16* __restrict__ hid,
              const __hip_bfloat16* __restrict__ W2bf,
              const float* __restrict__ b2,
              float* __restrict__ outp)
{
  const int tid = threadIdx.x;
  const int w = tid >> 6, lane = tid & 63;
  const int l16 = lane & 15, quad = lane >> 4;
  const int mb = (blockIdx.x * 4 + w) * 32;

  f32x4 acc[2][2];
#pragma unroll
  for (int s = 0; s < 2; ++s)
#pragma unroll
    for (int t = 0; t < 2; ++t) acc[s][t] = (f32x4)0.f;

#pragma unroll 4
  for (int kc = 0; kc < 16; ++kc) {
    s16x8 a0 = *(const s16x8*)(hid + (size_t)(mb + l16) * 512 + kc * 32 + quad * 8);
    s16x8 a1 = *(const s16x8*)(hid + (size_t)(mb + 16 + l16) * 512 + kc * 32 + quad * 8);
#pragma unroll
    for (int t = 0; t < 2; ++t) {
      s16x8 bfr = *(const s16x8*)(W2bf + (size_t)(t * 16 + l16) * 512 + kc * 32 + quad * 8);
      acc[0][t] = __builtin_amdgcn_mfma_f32_16x16x32_bf16(a0, bfr, acc[0][t], 0, 0, 0);
      acc[1][t] = __builtin_amdgcn_mfma_f32_16x16x32_bf16(a1, bfr, acc[1][t], 0, 0, 0);
    }
  }
#pragma unroll
  for (int t = 0; t < 2; ++t) {
    const int p = t * 16 + l16;
    if (p < 24) {
      float bv = b2[p];
#pragma unroll
      for (int s = 0; s < 2; ++s)
#pragma unroll
        for (int r = 0; r < 4; ++r) {
          int m = mb + s * 16 + quad * 4 + r;
          int bbi = m >> 9, it = m & 3, f = (m >> 2) & 127;
          outp[(size_t)bbi * 12288 + (it * 24 + p) * 128 + f] = acc[s][t][r] + bv;
        }
    }
  }
}

// ---------------- fallback fused K2 (R1-verified) if ws too small for hid ----------------
extern "C" __global__ __launch_bounds__(256)
void mwhf_k2f(const __hip_bfloat16* __restrict__ t0g,
              const __hip_bfloat16* __restrict__ W1bf,
              const __hip_bfloat16* __restrict__ W2bf,
              const float* __restrict__ b1, const float* __restrict__ b2,
              float* __restrict__ outp)
{
  __shared__ __align__(16) char smem[147456];
  s16x8* Av   = (s16x8*)smem;
  s16x8* W1v  = (s16x8*)(smem + 16384);
  s16x8* W2v  = (s16x8*)(smem + 16384);
  float* red  = (float*)(smem + 49152);
  __hip_bfloat16* hid = (__hip_bfloat16*)(smem + 81920);
  s16x8* hidv = (s16x8*)(smem + 81920);

  const int tid = threadIdx.x;
  const int m0 = blockIdx.x * 64;
  const int w = tid >> 6, lane = tid & 63;
  const int l16 = lane & 15, quad = lane >> 4;

  {
    const s16x8* src = (const s16x8*)(t0g + (size_t)m0 * 128);
    for (int e = tid; e < 1024; e += 256) {
      int m = e >> 4, c = e & 15;
      Av[m * 16 + (c ^ (m & 7))] = src[e];
    }
  }
  f32x4 acc[4][4];
  for (int nh = 0; nh < 2; ++nh) {
    __syncthreads();
    {
      const s16x8* src = (const s16x8*)W1bf + (size_t)nh * 4096;
      for (int e = tid; e < 4096; e += 256) {
        int n = e >> 4, c = e & 15;
        W1v[n * 16 + (c ^ (n & 7))] = src[e];
      }
    }
    __syncthreads();
#pragma unroll
    for (int s = 0; s < 4; ++s)
#pragma unroll
      for (int t = 0; t < 4; ++t) acc[s][t] = (f32x4)0.f;
#pragma unroll
    for (int ks = 0; ks < 4; ++ks) {
      s16x8 a[4];
#pragma unroll
      for (int s = 0; s < 4; ++s)
        a[s] = Av[(s * 16 + l16) * 16 + ((ks * 4 + quad) ^ (l16 & 7))];
#pragma unroll
      for (int t = 0; t < 4; ++t) {
        int nl = w * 64 + t * 16 + l16;
        s16x8 bfr = W1v[nl * 16 + ((ks * 4 + quad) ^ (nl & 7))];
#pragma unroll
        for (int s = 0; s < 4; ++s)
          acc[s][t] = __builtin_amdgcn_mfma_f32_16x16x32_bf16(a[s], bfr, acc[s][t], 0, 0, 0);
      }
    }
#pragma unroll
    for (int t = 0; t < 4; ++t) {
      int nabs = nh * 256 + w * 64 + t * 16 + l16;
      float bv = b1[nabs];
#pragma unroll
      for (int s = 0; s < 4; ++s)
#pragma unroll
        for (int r = 0; r < 4; ++r) {
          int m = s * 16 + quad * 4 + r;
          float h = fmaxf(acc[s][t][r] + bv, 0.f);
          hid[m * 512 + (nabs ^ ((m & 7) << 3))] = __float2bfloat16(h);
        }
    }
  }
  __syncthreads();
  {
    const s16x8* src = (const s16x8*)W2bf;
    for (int e = tid; e < 2048; e += 256) {
      int p = e >> 6, c = e & 63;
      W2v[p * 64 + (c ^ (p & 7))] = src[e];
    }
  }
  __syncthreads();
  {
    f32x4 a2[2];
    a2[0] = (f32x4)0.f; a2[1] = (f32x4)0.f;
    const int m = w * 16 + l16;
#pragma unroll 4
    for (int ks = 0; ks < 16; ++ks) {
      s16x8 av = hidv[m * 64 + ((ks * 4 + quad) ^ (l16 & 7))];
#pragma unroll
      for (int t = 0; t < 2; ++t) {
        s16x8 bfr = W2v[(t * 16 + l16) * 64 + ((ks * 4 + quad) ^ (l16 & 7))];
        a2[t] = __builtin_amdgcn_mfma_f32_16x16x32_bf16(av, bfr, a2[t], 0, 0, 0);
      }
    }
#pragma unroll
    for (int t = 0; t < 2; ++t)
#pragma unroll
      for (int r = 0; r < 4; ++r) {
        int p = t * 16 + l16;
        if (p < 24) red[(w * 16 + quad * 4 + r) * 25 + p] = a2[t][r];
      }
  }
  __syncthreads();
  {
    const int bbi = m0 >> 9;
    const int f0 = (m0 >> 2) & 127;
    for (int e = tid; e < 1536; e += 256) {
      int fi = e & 15;
      int rest = e >> 4;
      int p = rest % 24;
      int it = rest / 24;
      outp[(size_t)bbi * 12288 + rest * 128 + f0 + fi] = red[(fi * 4 + it) * 25 + p] + b2[p];
    }
  }
}

extern "C" void kernel_launch(void* const* d_in, const int* in_sizes, int n_in,
                              void* d_out, int out_size, void* d_ws, size_t ws_size,
                              hipStream_t stream) {
  (void)in_sizes; (void)n_in; (void)out_size;
  const float* trend = (const float*)d_in[0];
  const float* sc    = (const float*)d_in[1];
  const float* sf    = (const float*)d_in[2];
  const float* rs    = (const float*)d_in[3];
  const float* W_t   = (const float*)d_in[4];
  const float* b_t   = (const float*)d_in[5];
  const float* W_c   = (const float*)d_in[6];
  const float* b_c   = (const float*)d_in[7];
  const float* W_f   = (const float*)d_in[8];
  const float* b_f   = (const float*)d_in[9];
  const float* W_r   = (const float*)d_in[10];
  const float* b_r   = (const float*)d_in[11];
  const float* alpha = (const float*)d_in[12];
  const float* W1    = (const float*)d_in[13];
  const float* b1    = (const float*)d_in[14];
  const float* W2    = (const float*)d_in[15];
  const float* b2    = (const float*)d_in[16];

  char* ws = (char*)d_ws;
  __hip_bfloat16* t0   = (__hip_bfloat16*)(ws + kOffT0);
  __hip_bfloat16* W1bf = (__hip_bfloat16*)(ws + kOffW1);
  __hip_bfloat16* W2bf = (__hip_bfloat16*)(ws + kOffW2);
  __hip_bfloat16* BtH  = (__hip_bfloat16*)(ws + kOffBt);
  __hip_bfloat16* BtM  = BtH + 12288;
  __hip_bfloat16* BtL  = BtM + 12288;
  float* bsum = (float*)(ws + kOffBsum);
  float* z2w  = (float*)(ws + kOffZ2);
  float* zw   = (float*)(ws + kOffZ);
  __hip_bfloat16* hid = (__hip_bfloat16*)(ws + kOffHid);
  float* outp = (float*)d_out;

  hipLaunchKernelGGL(mwhf_prep, dim3(73), dim3(256), 0, stream,
                     W1, W2, W_t, W_c, W_f, W_r, b_t, b_c, b_f, b_r,
                     W1bf, W2bf, BtH, BtM, BtL, bsum);
  if (ws_size >= kWsNew) {
    hipLaunchKernelGGL(mwhf_k1a, dim3(4096), dim3(256), 0, stream,
                       trend, sc, sf, rs, BtH, BtM, BtL, bsum, zw, z2w);
    hipLaunchKernelGGL(mwhf_k1b, dim3(4096), dim3(256), 0, stream,
                       zw, z2w, alpha, t0);
  } else {
    hipLaunchKernelGGL(mwhf_k1, dim3(4096), dim3(256), 0, stream,
                       trend, sc, sf, rs, BtH, BtM, BtL, bsum, alpha, t0);
  }
  if (ws_size >= kWsSplit) {
    hipLaunchKernelGGL(mwhf_k2a, dim3(2048), dim3(256), 0, stream, t0, W1bf, b1, hid);
    hipLaunchKernelGGL(mwhf_k2b, dim3(512), dim3(256), 0, stream, hid, W2bf, b2, outp);
  } else {
    hipLaunchKernelGGL(mwhf_k2f, dim3(1024), dim3(256), 0, stream,
                       t0, W1bf, W2bf, b1, b2, outp);
  }
}

// Round 6
// 365.289 us; speedup vs baseline: 1.1101x; 1.1101x over previous
//
#include <hip/hip_runtime.h>
#include <hip/hip_bf16.h>

namespace {
constexpr int kL = 720, kF = 128;
constexpr int kWin = 15;
constexpr float kEps = 1e-6f;
constexpr float kMaxN = 1.0f - 1e-5f;
constexpr int kT0off = 360;   // (30-15)*24: only last 15 segments matter
constexpr int ZTR = 132;      // zt row stride (floats), +4 pad
constexpr int AROW = 104;     // A lds row stride (bf16): 96 + 8 pad
// ws offsets
constexpr size_t kOffT0   = 0;                    // 16 MiB bf16 t0
constexpr size_t kOffW1   = 16777216;             // 128 KiB bf16 W1 [n][k]
constexpr size_t kOffW2   = kOffW1 + 131072;      // 32 KiB bf16 W2 [p][k]
constexpr size_t kOffBt   = kOffW2 + 32768;       // 72 KiB: BtH/BtM/BtL [128][96] bf16
constexpr size_t kOffBsum = kOffBt + 73728;       // 512 B fp32
}

typedef float f32x4 __attribute__((ext_vector_type(4)));
typedef short s16x8 __attribute__((ext_vector_type(8)));

__device__ __forceinline__ float rcp_f(float x) { return __builtin_amdgcn_rcpf(x); }
__device__ __forceinline__ float sqrt_f(float x) { return __builtin_amdgcn_sqrtf(x); }
__device__ __forceinline__ float tanh_f(float x) {          // x >= 0
  float t = __builtin_amdgcn_exp2f(x * -2.8853900817779268f);
  return (1.0f - t) * rcp_f(1.0f + t);
}
__device__ __forceinline__ float artanh_f(float n) {        // n >= 0
  float nc = fminf(n, 1.0f - 1e-7f);
  return 0.34657359027997264f * __builtin_amdgcn_logf((1.0f + nc) * rcp_f(1.0f - nc));
}

// DPP butterfly add helpers (VALU-latency cross-lane, no LDS pipe).
template<int CTRL>
__device__ __forceinline__ float dpp_add(float v) {
  int mv = __builtin_amdgcn_update_dpp(0, __float_as_int(v), CTRL, 0xF, 0xF, false);
  return v + __int_as_float(mv);
}
__device__ __forceinline__ float sum16(float v) {
  v = dpp_add<0xB1>(v);
  v = dpp_add<0x4E>(v);
  v = dpp_add<0x141>(v);
  v = dpp_add<0x128>(v);
  return v;
}
__device__ __forceinline__ float sum64(float v) {
  v = sum16(v);
  v += __shfl_xor(v, 16);
  v += __shfl_xor(v, 32);
  return v;
}
__device__ __forceinline__ float rlane(float v, int i) {
  return __int_as_float(__builtin_amdgcn_readlane(__float_as_int(v), i));
}

// ---------------- prep: weight repack (bf16 W1/W2 + 3-level split Bt + bsum) ----------------
extern "C" __global__ __launch_bounds__(256)
void mwhf_prep(const float* __restrict__ W1, const float* __restrict__ W2,
               const float* __restrict__ W_t, const float* __restrict__ W_c,
               const float* __restrict__ W_f, const float* __restrict__ W_r,
               const float* __restrict__ b_t, const float* __restrict__ b_c,
               const float* __restrict__ b_f, const float* __restrict__ b_r,
               __hip_bfloat16* __restrict__ W1bf, __hip_bfloat16* __restrict__ W2bf,
               __hip_bfloat16* __restrict__ BtH, __hip_bfloat16* __restrict__ BtM,
               __hip_bfloat16* __restrict__ BtL, float* __restrict__ bsum)
{
  const int b = blockIdx.x, tid = threadIdx.x;
  if (b < 64) {                       // W1 [128k][512n] -> W1bf[n][k]
    const int n0 = b * 8;
    for (int e = tid; e < 1024; e += 256) {
      int n_l = e & 7, k = e >> 3;
      W1bf[(size_t)(n0 + n_l) * 128 + k] = __float2bfloat16(W1[(size_t)k * 512 + n0 + n_l]);
    }
  } else if (b < 68) {                // W2 [512k][24p] -> W2bf[p][k], rows 24..31 zero
    const int k0 = (b - 64) * 128;
    for (int e = tid; e < 4096; e += 256) {
      int p = e >> 7, k_l = e & 127;
      float v = (p < 24) ? W2[(size_t)(k0 + k_l) * 24 + p] : 0.0f;
      W2bf[(size_t)p * 512 + k0 + k_l] = __float2bfloat16(v);
    }
  } else if (b < 72) {                // Bt[d][k=st*24+s] = W_st[s][d], 3-level bf16 split
    const int st = b - 68;
    const float* src = (st == 0) ? W_t : (st == 1) ? W_c : (st == 2) ? W_f : W_r;
    for (int e = tid; e < 3072; e += 256) {
      int s = e >> 7, d = e & 127;
      float x = src[e];                       // src[s*128 + d]
      __hip_bfloat16 h = __float2bfloat16(x);
      float r1 = x - __bfloat162float(h);
      __hip_bfloat16 m = __float2bfloat16(r1);
      float r2 = r1 - __bfloat162float(m);
      const int o = d * 96 + st * 24 + s;
      BtH[o] = h;
      BtM[o] = m;
      BtL[o] = __float2bfloat16(r2);
    }
  } else {
    if (tid < 128) bsum[tid] = b_t[tid] + b_c[tid] + b_f[tid] + b_r[tid];
  }
}

// ---------------- K1 (R4-verified, 156us): 3-level bf16 MFMA GEMM + expmap0 + recurrence ----
extern "C" __global__ __launch_bounds__(256, 4)
void mwhf_k1(const float* __restrict__ trend,
             const float* __restrict__ seas_c,
             const float* __restrict__ seas_f,
             const float* __restrict__ resid,
             const __hip_bfloat16* __restrict__ BtH,
             const __hip_bfloat16* __restrict__ BtM,
             const __hip_bfloat16* __restrict__ BtL,
             const float* __restrict__ bsum,
             const float* __restrict__ alpha,
             __hip_bfloat16* __restrict__ t0_out)
{
  __shared__ __align__(16) char smem_raw[3 * 64 * AROW * 2];   // 39936 B: A hi/mid/lo union zt
  __shared__ float z2s[80];
  __shared__ float pds[80];

  float* ublk = (float*)smem_raw;
  __hip_bfloat16* Ah = (__hip_bfloat16*)smem_raw;
  __hip_bfloat16* Am = Ah + 64 * AROW;
  __hip_bfloat16* Al = Am + 64 * AROW;

  const int tid = threadIdx.x;
  const int bix = blockIdx.x;
  const int bb = (bix & 7) * 16 + (bix >> 8);
  const int f0 = ((bix >> 3) & 31) * 4;
  const int row0 = bb * 128 + f0;

  for (int e = tid; e < 192; e += 256) {
    int rr = e / 48, cc = e - rr * 48;
    int off = (rr * 16 + 15) * AROW;
    ((unsigned int*)(Ah + off))[cc] = 0u;
    ((unsigned int*)(Am + off))[cc] = 0u;
    ((unsigned int*)(Al + off))[cc] = 0u;
  }
  {
    const float* ptrs[4] = {trend, seas_c, seas_f, resid};
    for (int e = tid; e < 1440; e += 256) {
      int seg = e / 96;
      int k = e - seg * 96;
      int st = k / 24, s = k - st * 24;
      const float* p = ptrs[st];
      float4 v = *(const float4*)&p[(size_t)(bb * kL + kT0off + seg * 24 + s) * kF + f0];
      float xv[4] = {v.x, v.y, v.z, v.w};
#pragma unroll
      for (int f = 0; f < 4; ++f) {
        int m = f * 16 + seg;
        __hip_bfloat16 h = __float2bfloat16(xv[f]);
        float r1 = xv[f] - __bfloat162float(h);
        __hip_bfloat16 mm = __float2bfloat16(r1);
        float r2 = r1 - __bfloat162float(mm);
        Ah[m * AROW + k] = h;
        Am[m * AROW + k] = mm;
        Al[m * AROW + k] = __float2bfloat16(r2);
      }
    }
  }
  __syncthreads();

  const int w = tid >> 6;
  const int lane = tid & 63;
  const int l16 = lane & 15, quad = lane >> 4;

  f32x4 acc0[8];
  float scale4[4], zz4[4];
  {
    s16x8 ah[3], am[3], al[3];
    const int abase = (w * 16 + l16) * AROW + quad * 8;
#pragma unroll
    for (int ks = 0; ks < 3; ++ks) {
      ah[ks] = *(const s16x8*)(Ah + abase + ks * 32);
      am[ks] = *(const s16x8*)(Am + abase + ks * 32);
      al[ks] = *(const s16x8*)(Al + abase + ks * 32);
    }
#pragma unroll
    for (int t = 0; t < 8; ++t) acc0[t] = (f32x4)0.f;
    const __hip_bfloat16* bhp = BtH + l16 * 96 + quad * 8;
    const __hip_bfloat16* bmp = BtM + l16 * 96 + quad * 8;
    const __hip_bfloat16* blp = BtL + l16 * 96 + quad * 8;
#pragma unroll
    for (int t = 0; t < 8; ++t) {
#pragma unroll
      for (int ks = 0; ks < 3; ++ks) {
        s16x8 bh = *(const s16x8*)(bhp + t * 1536 + ks * 32);
        s16x8 bm = *(const s16x8*)(bmp + t * 1536 + ks * 32);
        s16x8 bl = *(const s16x8*)(blp + t * 1536 + ks * 32);
        acc0[t] = __builtin_amdgcn_mfma_f32_16x16x32_bf16(ah[ks], bh, acc0[t], 0, 0, 0);
        acc0[t] = __builtin_amdgcn_mfma_f32_16x16x32_bf16(am[ks], bh, acc0[t], 0, 0, 0);
        acc0[t] = __builtin_amdgcn_mfma_f32_16x16x32_bf16(ah[ks], bm, acc0[t], 0, 0, 0);
        acc0[t] = __builtin_amdgcn_mfma_f32_16x16x32_bf16(al[ks], bh, acc0[t], 0, 0, 0);
        acc0[t] = __builtin_amdgcn_mfma_f32_16x16x32_bf16(ah[ks], bl, acc0[t], 0, 0, 0);
        acc0[t] = __builtin_amdgcn_mfma_f32_16x16x32_bf16(am[ks], bm, acc0[t], 0, 0, 0);
      }
    }
    float part[4] = {0.f, 0.f, 0.f, 0.f};
#pragma unroll
    for (int t = 0; t < 8; ++t) {
      float bv = bsum[t * 16 + l16];
#pragma unroll
      for (int r = 0; r < 4; ++r) {
        float v = acc0[t][r] + bv;
        acc0[t][r] = v;
        part[r] += v * v;
      }
    }
#pragma unroll
    for (int r = 0; r < 4; ++r) part[r] = sum16(part[r]);
#pragma unroll
    for (int r = 0; r < 4; ++r) {
      float v2 = part[r];
      float nv = sqrt_f(fmaxf(v2, 1e-12f));
      float sc = tanh_f(nv) * rcp_f(nv);
      float y2 = sc * sc * v2;
      float yn = sqrt_f(fmaxf(y2, 1e-12f));
      float proj = (yn > kMaxN) ? (kMaxN * rcp_f(yn)) : 1.0f;
      scale4[r] = sc * proj;
      zz4[r] = y2 * proj * proj;
    }
  }
  __syncthreads();
  {
#pragma unroll
    for (int r = 0; r < 4; ++r) {
      int row = quad * 4 + r;
      if (row < kWin) {
#pragma unroll
        for (int t = 0; t < 8; ++t)
          ublk[(w * kWin + row) * ZTR + t * 16 + l16] = acc0[t][r] * scale4[r];
        if (l16 == 0) z2s[w * 20 + row] = zz4[r];
      }
    }
  }
  __syncthreads();

  {
    const int l = lane;
    float zx[19], zy[19];
#pragma unroll
    for (int j = 0; j < 15; ++j) {
      float2 v = *(const float2*)&ublk[(w * kWin + j) * ZTR + 2 * l];
      zx[j] = v.x; zy[j] = v.y;
    }
    {
      float pd[14];
#pragma unroll
      for (int j = 0; j < 14; ++j) pd[j] = zx[j] * zx[j + 1] + zy[j] * zy[j + 1];
#pragma unroll
      for (int j = 0; j < 14; ++j) pd[j] = sum64(pd[j]);
      if (l == 0) {
#pragma unroll
        for (int j = 0; j < 14; ++j) pds[w * 20 + j] = pd[j];
      }
    }
    const float alp = alpha[0];
    const float cw14 = (l < 14)
        ? __builtin_amdgcn_exp2f((float)(13 - l) * -0.15200309344504997f) * 0.12966260f
        : 0.f;
#pragma unroll
    for (int it = 0; it < 4; ++it) {
      float cA = 0.f, cB = 0.f, cW = 0.f;
      if (l < 14) {
        float dp = pds[w * 20 + it + l];
        float x2 = z2s[w * 20 + it + l];
        float y2 = z2s[w * 20 + it + l + 1];
        cA = 1.f - 2.f * dp + y2;
        cB = 1.f - x2;
        float den = fmaxf(1.f - 2.f * dp + x2 * y2, kEps);
        float invd = rcp_f(den);
        float d2 = (cA * cA * x2 - 2.f * cA * cB * dp + cB * cB * y2) * (invd * invd);
        float n = sqrt_f(fmaxf(d2, 1e-12f));
        float coef = fmaxf(cB, kEps) * artanh_f(n) * rcp_f(n);
        cW = cw14 * coef * invd;
      }
      float avx = 0.f, avy = 0.f;
#pragma unroll
      for (int i = 0; i < 14; ++i) {
        float sA = rlane(cA, i), sB = rlane(cB, i), sW = rlane(cW, i);
        float tx = sB * zx[it + i + 1] - sA * zx[it + i];
        float ty = sB * zy[it + i + 1] - sA * zy[it + i];
        avx += sW * tx;
        avy += sW * ty;
      }
      float vx = alp * avx, vy = alp * avy;
      const int pl = it + 14;
      float x2l = z2s[w * 20 + pl];
      float v2 = vx * vx + vy * vy;
      float xdv = zx[pl] * vx + zy[pl] * vy;
      v2 = sum64(v2);
      xdv = sum64(xdv);
      float nv = sqrt_f(fmaxf(v2, 1e-12f));
      float lam = 2.f * rcp_f(fmaxf(1.f - x2l, kEps));
      float co = tanh_f(0.5f * lam * nv) * rcp_f(nv);
      float s2 = co * co * v2;
      float xy = co * xdv;
      float P = 1.f + 2.f * xy + s2;
      float Q = 1.f - x2l;
      float den2 = fmaxf(1.f + 2.f * xy + x2l * s2, kEps);
      float invd2 = rcp_f(den2);
      float znx = (P * zx[pl] + Q * co * vx) * invd2;
      float zny = (P * zy[pl] + Q * co * vy) * invd2;
      float zn2 = (P * P * x2l + 2.f * P * Q * xy + Q * Q * s2) * (invd2 * invd2);
      float pdn = (P * x2l + Q * xy) * invd2;
      float yn = sqrt_f(fmaxf(zn2, 1e-12f));
      float proj = (yn > kMaxN) ? (kMaxN * rcp_f(yn)) : 1.f;
      znx *= proj; zny *= proj;
      zn2 *= proj * proj;
      pdn *= proj;
      zx[15 + it] = znx; zy[15 + it] = zny;
      if (l == 0) {
        z2s[w * 20 + 15 + it] = zn2;
        pds[w * 20 + 14 + it] = pdn;
      }
      float n0 = sqrt_f(fmaxf(zn2, 1e-12f));
      float fac = artanh_f(n0) * rcp_f(n0);
      __hip_bfloat162 hv;
      hv.x = __float2bfloat16(fac * znx);
      hv.y = __float2bfloat16(fac * zny);
      *(__hip_bfloat162*)(t0_out + ((size_t)(row0 + w) * 4 + it) * 128 + 2 * l) = hv;
    }
  }
}

// ---------------- K2g: fused out = relu(t0 @ W1 + b1) @ W2 + b2, hid in LDS ----------------
// Phase 1 = verified k2a MFMA body (hid -> LDS, k2f's XOR swizzle).
// Phase 2 = verified k2b MFMA/epilogue (wave -> (m-half, p-tile)).
extern "C" __global__ __launch_bounds__(256, 4)
void mwhf_k2g(const __hip_bfloat16* __restrict__ t0g,
              const __hip_bfloat16* __restrict__ W1bf,
              const __hip_bfloat16* __restrict__ W2bf,
              const float* __restrict__ b1, const float* __restrict__ b2,
              float* __restrict__ outp)
{
  __shared__ __align__(16) __hip_bfloat16 hids[32 * 512];   // 32 KiB, XOR-swizzled
  s16x8* hidv = (s16x8*)hids;

  const int tid = threadIdx.x;
  const int w = tid >> 6, lane = tid & 63;
  const int l16 = lane & 15, quad = lane >> 4;
  const int mbase = blockIdx.x * 32;
  const int ng = w * 128;

  // ---- phase 1: hid = relu(t0 @ W1 + b1) -> LDS ----
  s16x8 afr[2][4];
#pragma unroll
  for (int s = 0; s < 2; ++s)
#pragma unroll
    for (int kc = 0; kc < 4; ++kc)
      afr[s][kc] = *(const s16x8*)(t0g + (size_t)(mbase + s * 16 + l16) * 128 + kc * 32 + quad * 8);

  f32x4 acc[2][8];
#pragma unroll
  for (int s = 0; s < 2; ++s)
#pragma unroll
    for (int t = 0; t < 8; ++t) acc[s][t] = (f32x4)0.f;

#pragma unroll
  for (int t = 0; t < 8; ++t) {
    const __hip_bfloat16* bp = W1bf + (size_t)(ng + t * 16 + l16) * 128 + quad * 8;
#pragma unroll
    for (int kc = 0; kc < 4; ++kc) {
      s16x8 bfr = *(const s16x8*)(bp + kc * 32);
      acc[0][t] = __builtin_amdgcn_mfma_f32_16x16x32_bf16(afr[0][kc], bfr, acc[0][t], 0, 0, 0);
      acc[1][t] = __builtin_amdgcn_mfma_f32_16x16x32_bf16(afr[1][kc], bfr, acc[1][t], 0, 0, 0);
    }
  }
#pragma unroll
  for (int t = 0; t < 8; ++t) {
    const int nl = ng + t * 16 + l16;      // 0..511
    float bv = b1[nl];
#pragma unroll
    for (int s = 0; s < 2; ++s)
#pragma unroll
      for (int r = 0; r < 4; ++r) {
        int m = s * 16 + quad * 4 + r;     // local row 0..31
        float h = fmaxf(acc[s][t][r] + bv, 0.f);
        hids[m * 512 + (nl ^ ((m & 7) << 3))] = __float2bfloat16(h);
      }
  }
  __syncthreads();

  // ---- phase 2: out = hid @ W2 + b2; wave -> (m-half s2i, p-tile t2) ----
  {
    const int s2i = w & 1, t2 = w >> 1;
    f32x4 a2 = (f32x4)0.f;
    const int mrow = s2i * 16 + l16;
#pragma unroll 4
    for (int kc = 0; kc < 16; ++kc) {
      s16x8 av = hidv[mrow * 64 + ((kc * 4 + quad) ^ (l16 & 7))];
      s16x8 bfr = *(const s16x8*)(W2bf + (size_t)(t2 * 16 + l16) * 512 + kc * 32 + quad * 8);
      a2 = __builtin_amdgcn_mfma_f32_16x16x32_bf16(av, bfr, a2, 0, 0, 0);
    }
    const int p = t2 * 16 + l16;
    if (p < 24) {
      float bv = b2[p];
#pragma unroll
      for (int r = 0; r < 4; ++r) {
        int m = mbase + s2i * 16 + quad * 4 + r;
        int bbi = m >> 9, it = m & 3, f = (m >> 2) & 127;
        outp[(size_t)bbi * 12288 + (it * 24 + p) * 128 + f] = a2[r] + bv;
      }
    }
  }
}

extern "C" void kernel_launch(void* const* d_in, const int* in_sizes, int n_in,
                              void* d_out, int out_size, void* d_ws, size_t ws_size,
                              hipStream_t stream) {
  (void)in_sizes; (void)n_in; (void)out_size; (void)ws_size;
  const float* trend = (const float*)d_in[0];
  const float* sc    = (const float*)d_in[1];
  const float* sf    = (const float*)d_in[2];
  const float* rs    = (const float*)d_in[3];
  const float* W_t   = (const float*)d_in[4];
  const float* b_t   = (const float*)d_in[5];
  const float* W_c   = (const float*)d_in[6];
  const float* b_c   = (const float*)d_in[7];
  const float* W_f   = (const float*)d_in[8];
  const float* b_f   = (const float*)d_in[9];
  const float* W_r   = (const float*)d_in[10];
  const float* b_r   = (const float*)d_in[11];
  const float* alpha = (const float*)d_in[12];
  const float* W1    = (const float*)d_in[13];
  const float* b1    = (const float*)d_in[14];
  const float* W2    = (const float*)d_in[15];
  const float* b2    = (const float*)d_in[16];

  char* ws = (char*)d_ws;
  __hip_bfloat16* t0   = (__hip_bfloat16*)(ws + kOffT0);
  __hip_bfloat16* W1bf = (__hip_bfloat16*)(ws + kOffW1);
  __hip_bfloat16* W2bf = (__hip_bfloat16*)(ws + kOffW2);
  __hip_bfloat16* BtH  = (__hip_bfloat16*)(ws + kOffBt);
  __hip_bfloat16* BtM  = BtH + 12288;
  __hip_bfloat16* BtL  = BtM + 12288;
  float* bsum = (float*)(ws + kOffBsum);
  float* outp = (float*)d_out;

  hipLaunchKernelGGL(mwhf_prep, dim3(73), dim3(256), 0, stream,
                     W1, W2, W_t, W_c, W_f, W_r, b_t, b_c, b_f, b_r,
                     W1bf, W2bf, BtH, BtM, BtL, bsum);
  hipLaunchKernelGGL(mwhf_k1, dim3(4096), dim3(256), 0, stream,
                     trend, sc, sf, rs, BtH, BtM, BtL, bsum, alpha, t0);
  hipLaunchKernelGGL(mwhf_k2g, dim3(2048), dim3(256), 0, stream,
                     t0, W1bf, W2bf, b1, b2, outp);
}